// Round 9
// baseline (759.585 us; speedup 1.0000x reference)
//
#include <hip/hip_runtime.h>

#define B_   8
#define L_   512
#define H_   768
#define NH_  12
#define DFF_ 3072
#define NL_  4
#define HD_  64
#define M_   4096

typedef __bf16 bf16x8 __attribute__((ext_vector_type(8)));
typedef float f32x4 __attribute__((ext_vector_type(4)));
typedef unsigned short u16x8 __attribute__((ext_vector_type(8)));

__device__ inline float bf2f(unsigned short u){
  union { unsigned int i; float f; } v; v.i = ((unsigned int)u) << 16; return v.f;
}
__device__ inline unsigned short f2bf(float f){
  union { float f; unsigned int i; } v; v.f = f;
  unsigned int x = v.i;
  return (unsigned short)((x + 0x7fffu + ((x >> 16) & 1u)) >> 16);
}
__device__ inline u16x8 addbf8(u16x8 a, u16x8 b){
  u16x8 o;
  #pragma unroll
  for (int j = 0; j < 8; j++) o[j] = f2bf(bf2f(a[j]) + bf2f(b[j]));
  return o;
}

// ---------------- weight prep: transpose fp32 [R][C] -> bf16 [C][R] ----------------
// 64x64 tiles, float4 reads (16B/lane), LDS transpose, u16x8 writes (16B/lane).
__global__ __launch_bounds__(256) void k_prep_weights(const float* __restrict__ Wq, const float* __restrict__ Wk,
                               const float* __restrict__ Wv, const float* __restrict__ Wo,
                               const float* __restrict__ W1, const float* __restrict__ W2,
                               unsigned short* __restrict__ wTall){
  __shared__ float tile[64][65];
  int id = blockIdx.x;
  int layer = id / 1728;
  int r = id % 1728;
  unsigned short* wt = wTall + (size_t)layer * 7077888;
  const float* src; unsigned short* dst; int R, C, tr, tilesC;
  if (r < 576){
    int mat = r / 144; tr = r % 144; R = 768; C = 768; tilesC = 12;
    const float* s;
    if (mat == 0) s = Wq; else if (mat == 1) s = Wk; else if (mat == 2) s = Wv; else s = Wo;
    src = s + (size_t)layer * 589824;
    dst = wt + (size_t)mat * 589824;
  } else if (r < 1152){
    tr = r - 576; R = 768; C = 3072; tilesC = 48;
    src = W1 + (size_t)layer * 2359296; dst = wt + 2359296;
  } else {
    tr = r - 1152; R = 3072; C = 768; tilesC = 12;
    src = W2 + (size_t)layer * 2359296; dst = wt + 4718592;
  }
  int r0 = (tr / tilesC) << 6, c0 = (tr % tilesC) << 6;
  int tid = threadIdx.x;
  int tx = tid & 15, ty = tid >> 4;   // 16x16, 4 rows per thread
  #pragma unroll
  for (int i = 0; i < 4; i++){
    int row = ty + i * 16;
    float4 v = *(const float4*)(src + (size_t)(r0 + row) * C + c0 + tx * 4);
    tile[row][tx * 4] = v.x; tile[row][tx * 4 + 1] = v.y;
    tile[row][tx * 4 + 2] = v.z; tile[row][tx * 4 + 3] = v.w;
  }
  __syncthreads();
  int rr = (tid & 7) * 8;
  #pragma unroll
  for (int i = 0; i < 2; i++){
    int col = (tid >> 3) + i * 32;
    u16x8 o;
    #pragma unroll
    for (int j = 0; j < 8; j++) o[j] = f2bf(tile[rr + j][col]);
    *(u16x8*)(dst + (size_t)(c0 + col) * R + r0 + rr) = o;
  }
}

// concat qkv bias per layer: [NL][2304]
__global__ void k_prep_bias(const float* __restrict__ bq, const float* __restrict__ bk,
                            const float* __restrict__ bv, float* __restrict__ out){
  int i = blockIdx.x * 256 + threadIdx.x; // 4*2304
  int layer = i / 2304, c = i % 2304;
  float v;
  if (c < 768) v = bq[layer * 768 + c];
  else if (c < 1536) v = bk[layer * 768 + c - 768];
  else v = bv[layer * 768 + c - 1536];
  out[i] = v;
}

// ---------------- embedding + LN (bf16 out only) ----------------
__global__ __launch_bounds__(256) void k_embed_ln(const int* __restrict__ ids, const int* __restrict__ tts,
                           const float* __restrict__ we, const float* __restrict__ pe,
                           const float* __restrict__ te, const float* __restrict__ g,
                           const float* __restrict__ b,
                           unsigned short* __restrict__ xb){
  int row = blockIdx.x;           // 4096
  int l = row & 511;
  int id = ids[row], tt = tts[row];
  int t = threadIdx.x;            // 256
  float v[3]; float s = 0.f, s2 = 0.f;
  #pragma unroll
  for (int i = 0; i < 3; i++){
    int c = t + i * 256;
    float val = we[(size_t)id * 768 + c] + pe[(size_t)l * 768 + c] + te[(size_t)tt * 768 + c];
    v[i] = val; s += val; s2 += val * val;
  }
  #pragma unroll
  for (int o = 32; o > 0; o >>= 1){ s += __shfl_down(s, o); s2 += __shfl_down(s2, o); }
  __shared__ float red[2][4];
  int wv = t >> 6;
  if ((t & 63) == 0){ red[0][wv] = s; red[1][wv] = s2; }
  __syncthreads();
  s = red[0][0] + red[0][1] + red[0][2] + red[0][3];
  s2 = red[1][0] + red[1][1] + red[1][2] + red[1][3];
  float mean = s * (1.f / 768.f);
  float var = s2 * (1.f / 768.f) - mean * mean;
  float rstd = rsqrtf(var + 1e-12f);
  #pragma unroll
  for (int i = 0; i < 3; i++){
    int c = t + i * 256;
    float nv = (v[i] - mean) * rstd * g[c] + b[c];
    xb[(size_t)row * 768 + c] = f2bf(nv);
  }
}

// ---------------- residual add (bf16 residual, + n2 extra bf16 partials) + LN ----------------
__global__ __launch_bounds__(256) void k_add_ln(unsigned short* __restrict__ xb,
                         const unsigned short* __restrict__ y,
                         const unsigned short* __restrict__ y2, int n2,
                         const float* __restrict__ g, const float* __restrict__ b){
  int row = blockIdx.x;
  int t = threadIdx.x;
  float v[3]; float s = 0.f, s2 = 0.f;
  #pragma unroll
  for (int i = 0; i < 3; i++){
    int c = t + i * 256;
    size_t idx = (size_t)row * 768 + c;
    float val = bf2f(xb[idx]) + bf2f(y[idx]);
    for (int q = 0; q < n2; q++) val += bf2f(y2[(size_t)q * 4096 * 768 + idx]);
    v[i] = val; s += val; s2 += val * val;
  }
  #pragma unroll
  for (int o = 32; o > 0; o >>= 1){ s += __shfl_down(s, o); s2 += __shfl_down(s2, o); }
  __shared__ float red[2][4];
  int wv = t >> 6;
  if ((t & 63) == 0){ red[0][wv] = s; red[1][wv] = s2; }
  __syncthreads();
  s = red[0][0] + red[0][1] + red[0][2] + red[0][3];
  s2 = red[1][0] + red[1][1] + red[1][2] + red[1][3];
  float mean = s * (1.f / 768.f);
  float var = s2 * (1.f / 768.f) - mean * mean;
  float rstd = rsqrtf(var + 1e-12f);
  #pragma unroll
  for (int i = 0; i < 3; i++){
    int c = t + i * 256;
    float nv = (v[i] - mean) * rstd * g[c] + b[c];
    xb[(size_t)row * 768 + c] = f2bf(nv);
  }
}

// ---------------- bf16 MFMA GEMM, m97 structure (single 32KB buffer) + T2 swizzle ----------------
// C[M][N] = A[M][Kslice] @ BT[N][K]^T + bias, bf16 out. blockIdx.z = K-slice;
// z>0 writes bias-free partial to Cout2[(z-1)*M*N]. ACT 0: none; 1: gelu.
// __launch_bounds__(256,4): cap unified regs at 128 -> 4 blocks/CU (blocks/CU is THE lever).
template<int ACT>
__global__ __launch_bounds__(256, 4) void k_gemm(const unsigned short* __restrict__ A,
                                              const unsigned short* __restrict__ BT,
                                              const float* __restrict__ bias,
                                              unsigned short* __restrict__ Cout,
                                              unsigned short* __restrict__ Cout2,
                                              int M, int N, int K, int Ksub){
  __shared__ __attribute__((aligned(16))) unsigned short smem[16384]; // As | Bs, 32 KB
  unsigned short* As = smem;
  unsigned short* Bs = smem + 8192;
  int tid = threadIdx.x;
  int lane = tid & 63, wave = tid >> 6;
  int lr = lane & 15, lg = lane >> 4;

  // XCD-aware swizzle of flat tile id (nwg % 8 == 0 in all launches)
  int gx = gridDim.x;
  int nwg = gx * gridDim.y;
  int flat = blockIdx.y * gx + blockIdx.x;
  int cpx = nwg >> 3;
  int swz = (flat & 7) * cpx + (flat >> 3);
  int bx = swz % gx, by = swz / gx;

  int bm0 = by * 128, bn0 = bx * 128;
  int wr = wave >> 1, wc = wave & 1;
  int kz = blockIdx.z * Ksub;

  f32x4 acc[4][4];
  #pragma unroll
  for (int m = 0; m < 4; m++)
    #pragma unroll
    for (int n = 0; n < 4; n++)
      acc[m][n] = (f32x4){0.f, 0.f, 0.f, 0.f};

  // per-lane pre-swizzled source column (T2, m173 pattern)
  int scol = (((lane & 7) ^ (lane >> 3)) << 3);
  const unsigned short* gaBase = A + (size_t)(bm0 + (lane >> 3)) * K + kz + scol;
  const unsigned short* gbBase = BT + (size_t)(bn0 + (lane >> 3)) * K + kz + scol;

  int nk = Ksub >> 6;
  for (int t = 0; t < nk; t++){
    if (t) __syncthreads();           // all waves done reading previous tile
    const unsigned short* gA = gaBase + (t << 6);
    const unsigned short* gB = gbBase + (t << 6);
    #pragma unroll
    for (int i = 0; i < 4; i++){
      size_t ro = (size_t)((wave * 4 + i) * 8) * K;
      __builtin_amdgcn_global_load_lds(
        (const __attribute__((address_space(1))) void*)(gA + ro),
        (__attribute__((address_space(3))) void*)(As + (wave * 4 + i) * 512), 16, 0, 0);
      __builtin_amdgcn_global_load_lds(
        (const __attribute__((address_space(1))) void*)(gB + ro),
        (__attribute__((address_space(3))) void*)(Bs + (wave * 4 + i) * 512), 16, 0, 0);
    }
    __syncthreads();                  // vmcnt(0)+barrier: tile resident
    #pragma unroll
    for (int kk = 0; kk < 2; kk++){
      bf16x8 av[4], bv[4];
      #pragma unroll
      for (int m = 0; m < 4; m++)
        av[m] = *(const bf16x8*)(As + (wr * 64 + m * 16 + lr) * 64 + (((4 * kk + lg) ^ (lr & 7)) << 3));
      #pragma unroll
      for (int n = 0; n < 4; n++)
        bv[n] = *(const bf16x8*)(Bs + (wc * 64 + n * 16 + lr) * 64 + (((4 * kk + lg) ^ (lr & 7)) << 3));
      #pragma unroll
      for (int m = 0; m < 4; m++)
        #pragma unroll
        for (int n = 0; n < 4; n++)
          acc[m][n] = __builtin_amdgcn_mfma_f32_16x16x32_bf16(av[m], bv[n], acc[m][n], 0, 0, 0);
    }
  }
  __syncthreads();                    // safe to reuse smem for epilogue

  // epilogue: stage bf16 C tile [128][128] in LDS, then linear coalesced stores
  int r0 = wr * 64 + 4 * lg;
  int c0 = wc * 64 + lr;
  unsigned short* cs = smem;
  bool z0 = (blockIdx.z == 0);
  #pragma unroll
  for (int n = 0; n < 4; n++){
    int c = c0 + 16 * n;
    float bsv = z0 ? bias[bn0 + c] : 0.f;
    #pragma unroll
    for (int m = 0; m < 4; m++)
      #pragma unroll
      for (int j = 0; j < 4; j++){
        float v = acc[m][n][j] + bsv;
        if (ACT == 1) v = 0.5f * v * (1.f + erff(v * 0.70710678118f));
        cs[(r0 + m * 16 + j) * 128 + c] = f2bf(v);
      }
  }
  __syncthreads();
  unsigned short* Cb = z0 ? Cout : (Cout2 + (size_t)(blockIdx.z - 1) * M * N);
  #pragma unroll
  for (int p = 0; p < 8; p++){
    int idx = p * 2048 + tid * 8;
    int row = idx >> 7, col = idx & 127;
    u16x8 v = *(const u16x8*)(cs + idx);
    *(u16x8*)(Cb + (size_t)(bm0 + row) * N + bn0 + col) = v;
  }
}

// ---------------- fused FF1 reduce: h = gelu(h + p1) (bf16, x8 vectorized) ----------------
__global__ __launch_bounds__(256) void k_gelu_reduce(unsigned short* __restrict__ h,
                                                     const unsigned short* __restrict__ p1){
  size_t i = ((size_t)blockIdx.x * 256 + threadIdx.x) * 8;
  u16x8 a = *(const u16x8*)(h + i);
  u16x8 b = *(const u16x8*)(p1 + i);
  u16x8 o;
  #pragma unroll
  for (int j = 0; j < 8; j++){
    float v = bf2f(a[j]) + bf2f(b[j]);
    v = 0.5f * v * (1.f + erff(v * 0.70710678118f));
    o[j] = f2bf(v);
  }
  *(u16x8*)(h + i) = o;
}

// ---------------- MFMA flash attention (reads qkv = qkvA + qkvB, fused split-K reduce) ----------------
__global__ __launch_bounds__(256) void k_attn_mfma(const unsigned short* __restrict__ qkv,
                                                   const unsigned short* __restrict__ qkvp,
                                                   const int* __restrict__ mask,
                                                   unsigned short* __restrict__ ctx){
  int qt = blockIdx.x, h = blockIdx.y, b = blockIdx.z;
  int tid = threadIdx.x;
  int lane = tid & 63, w = tid >> 6;
  int lr = lane & 15, lg = lane >> 4;

  __shared__ __attribute__((aligned(16))) unsigned short Ks[64][72];
  __shared__ __attribute__((aligned(16))) unsigned short VsT[64][72];
  __shared__ __attribute__((aligned(16))) unsigned short Ps[4][16][72];
  __shared__ float biasS[64];

  int qrow = b * 512 + qt * 64 + w * 16 + lr;
  size_t qoff = (size_t)qrow * 2304 + h * 64 + lg * 8;
  bf16x8 qa[2];
  {
    u16x8 s0 = addbf8(*(const u16x8*)(qkv + qoff), *(const u16x8*)(qkvp + qoff));
    u16x8 s1 = addbf8(*(const u16x8*)(qkv + qoff + 32), *(const u16x8*)(qkvp + qoff + 32));
    qa[0] = *(bf16x8*)&s0;
    qa[1] = *(bf16x8*)&s1;
  }

  f32x4 oacc[4];
  #pragma unroll
  for (int dt = 0; dt < 4; dt++) oacc[dt] = (f32x4){0.f, 0.f, 0.f, 0.f};
  float mrow[4], lrow[4];
  #pragma unroll
  for (int j = 0; j < 4; j++){ mrow[j] = -1e30f; lrow[j] = 0.f; }

  for (int c = 0; c < 8; c++){
    __syncthreads();
    {
      int r = tid >> 2, d0 = (tid & 3) << 4;
      size_t off = (size_t)(b * 512 + c * 64 + r) * 2304 + 768 + h * 64 + d0;
      u16x8 k0 = addbf8(*(const u16x8*)(qkv + off), *(const u16x8*)(qkvp + off));
      u16x8 k1 = addbf8(*(const u16x8*)(qkv + off + 8), *(const u16x8*)(qkvp + off + 8));
      *(u16x8*)(&Ks[r][d0]) = k0;
      *(u16x8*)(&Ks[r][d0 + 8]) = k1;
    }
    {
      int kv = tid & 63, d0 = (tid >> 6) << 4;
      size_t off = (size_t)(b * 512 + c * 64 + kv) * 2304 + 1536 + h * 64 + d0;
      u16x8 v0 = addbf8(*(const u16x8*)(qkv + off), *(const u16x8*)(qkvp + off));
      u16x8 v1 = addbf8(*(const u16x8*)(qkv + off + 8), *(const u16x8*)(qkvp + off + 8));
      #pragma unroll
      for (int j2 = 0; j2 < 8; j2++){
        VsT[d0 + j2][kv] = (unsigned short)v0[j2];
        VsT[d0 + 8 + j2][kv] = (unsigned short)v1[j2];
      }
    }
    if (tid < 64) biasS[tid] = (1.f - (float)mask[b * 512 + c * 64 + tid]) * -1e9f;
    __syncthreads();

    f32x4 sacc[4];
    #pragma unroll
    for (int n = 0; n < 4; n++) sacc[n] = (f32x4){0.f, 0.f, 0.f, 0.f};
    #pragma unroll
    for (int kk = 0; kk < 2; kk++){
      bf16x8 kb[4];
      #pragma unroll
      for (int n = 0; n < 4; n++)
        kb[n] = *(const bf16x8*)(&Ks[lr + 16 * n][lg * 8 + 32 * kk]);
      #pragma unroll
      for (int n = 0; n < 4; n++)
        sacc[n] = __builtin_amdgcn_mfma_f32_16x16x32_bf16(qa[kk], kb[n], sacc[n], 0, 0, 0);
    }

    float pv[4][4];
    #pragma unroll
    for (int n = 0; n < 4; n++){
      float bsv = biasS[lr + 16 * n];
      #pragma unroll
      for (int j = 0; j < 4; j++) pv[n][j] = sacc[n][j] * 0.125f + bsv;
    }
    #pragma unroll
    for (int j = 0; j < 4; j++){
      float mx = fmaxf(fmaxf(pv[0][j], pv[1][j]), fmaxf(pv[2][j], pv[3][j]));
      mx = fmaxf(mx, __shfl_xor(mx, 1));
      mx = fmaxf(mx, __shfl_xor(mx, 2));
      mx = fmaxf(mx, __shfl_xor(mx, 4));
      mx = fmaxf(mx, __shfl_xor(mx, 8));
      float mnew = fmaxf(mrow[j], mx);
      float corr = __expf(mrow[j] - mnew);
      float ps = 0.f;
      #pragma unroll
      for (int n = 0; n < 4; n++){
        pv[n][j] = __expf(pv[n][j] - mnew);
        ps += pv[n][j];
      }
      ps += __shfl_xor(ps, 1);
      ps += __shfl_xor(ps, 2);
      ps += __shfl_xor(ps, 4);
      ps += __shfl_xor(ps, 8);
      lrow[j] = lrow[j] * corr + ps;
      mrow[j] = mnew;
      #pragma unroll
      for (int dt = 0; dt < 4; dt++) oacc[dt][j] *= corr;
    }

    #pragma unroll
    for (int n = 0; n < 4; n++)
      #pragma unroll
      for (int j = 0; j < 4; j++)
        Ps[w][4 * lg + j][lr + 16 * n] = f2bf(pv[n][j]);

    #pragma unroll
    for (int kk = 0; kk < 2; kk++){
      bf16x8 pa = *(const bf16x8*)(&Ps[w][lr][lg * 8 + 32 * kk]);
      bf16x8 vb[4];
      #pragma unroll
      for (int dt = 0; dt < 4; dt++)
        vb[dt] = *(const bf16x8*)(&VsT[lr + 16 * dt][lg * 8 + 32 * kk]);
      #pragma unroll
      for (int dt = 0; dt < 4; dt++)
        oacc[dt] = __builtin_amdgcn_mfma_f32_16x16x32_bf16(pa, vb[dt], oacc[dt], 0, 0, 0);
    }
  }

  #pragma unroll
  for (int j = 0; j < 4; j++){
    float inv = 1.f / lrow[j];
    int row = b * 512 + qt * 64 + w * 16 + 4 * lg + j;
    unsigned short* o = ctx + (size_t)row * 768 + h * 64;
    #pragma unroll
    for (int dt = 0; dt < 4; dt++)
      o[lr + 16 * dt] = f2bf(oacc[dt][j] * inv);
  }
}

// ---------------- span heads (bf16 input) ----------------
__global__ __launch_bounds__(256) void k_heads(const unsigned short* __restrict__ x,
                        const float* __restrict__ sw, const float* __restrict__ sb,
                        const float* __restrict__ ew, const float* __restrict__ eb,
                        const float* __restrict__ mw,
                        float* __restrict__ out, float* __restrict__ sproj, float* __restrict__ eproj){
  int row = blockIdx.x;
  int t = threadIdx.x;
  float a0 = 0.f, a1 = 0.f, a2 = 0.f, a3 = 0.f;
  #pragma unroll
  for (int i = 0; i < 3; i++){
    int c = t + i * 256;
    float v = bf2f(x[(size_t)row * 768 + c]);
    a0 += v * sw[c]; a1 += v * ew[c]; a2 += v * mw[c]; a3 += v * mw[768 + c];
  }
  #pragma unroll
  for (int o = 32; o > 0; o >>= 1){
    a0 += __shfl_down(a0, o); a1 += __shfl_down(a1, o);
    a2 += __shfl_down(a2, o); a3 += __shfl_down(a3, o);
  }
  __shared__ float red[4][4];
  int wv = t >> 6;
  if ((t & 63) == 0){ red[0][wv] = a0; red[1][wv] = a1; red[2][wv] = a2; red[3][wv] = a3; }
  __syncthreads();
  if (t == 0){
    float s0 = red[0][0] + red[0][1] + red[0][2] + red[0][3];
    float s1 = red[1][0] + red[1][1] + red[1][2] + red[1][3];
    float s2 = red[2][0] + red[2][1] + red[2][2] + red[2][3];
    float s3 = red[3][0] + red[3][1] + red[3][2] + red[3][3];
    out[row] = s0 + sb[0];
    out[4096 + row] = s1 + eb[0];
    sproj[row] = s2;
    eproj[row] = s3;
  }
}

__global__ __launch_bounds__(256) void k_match(const float* __restrict__ sproj, const float* __restrict__ eproj,
                        const float* __restrict__ mb, float* __restrict__ out){
  int idx = blockIdx.x * 256 + threadIdx.x;
  int j4 = idx & 127;
  int rest = idx >> 7;
  float sp = sproj[rest] + mb[0];
  const float* ep = eproj + ((rest >> 9) << 9) + j4 * 4;
  float4 r;
  r.x = sp + ep[0]; r.y = sp + ep[1]; r.z = sp + ep[2]; r.w = sp + ep[3];
  ((float4*)(out + 8192))[idx] = r;
}

extern "C" void kernel_launch(void* const* d_in, const int* in_sizes, int n_in,
                              void* d_out, int out_size, void* d_ws, size_t ws_size,
                              hipStream_t stream){
  (void)in_sizes; (void)n_in; (void)out_size; (void)ws_size;
  const int*   ids  = (const int*)d_in[0];
  const int*   tts  = (const int*)d_in[1];
  const int*   mask = (const int*)d_in[2];
  const float* we   = (const float*)d_in[3];
  const float* pe   = (const float*)d_in[4];
  const float* te   = (const float*)d_in[5];
  const float* eg   = (const float*)d_in[6];
  const float* ebv  = (const float*)d_in[7];
  const float* Wq   = (const float*)d_in[8];
  const float* bq   = (const float*)d_in[9];
  const float* Wk   = (const float*)d_in[10];
  const float* bk   = (const float*)d_in[11];
  const float* Wv   = (const float*)d_in[12];
  const float* bv   = (const float*)d_in[13];
  const float* Wo   = (const float*)d_in[14];
  const float* bo   = (const float*)d_in[15];
  const float* ag   = (const float*)d_in[16];
  const float* ab   = (const float*)d_in[17];
  const float* W1   = (const float*)d_in[18];
  const float* b1   = (const float*)d_in[19];
  const float* W2   = (const float*)d_in[20];
  const float* b2   = (const float*)d_in[21];
  const float* fg   = (const float*)d_in[22];
  const float* fb   = (const float*)d_in[23];
  const float* sw   = (const float*)d_in[24];
  const float* sb   = (const float*)d_in[25];
  const float* ew   = (const float*)d_in[26];
  const float* ebd  = (const float*)d_in[27];
  const float* mw   = (const float*)d_in[28];
  const float* mb   = (const float*)d_in[29];
  float* out = (float*)d_out;

  // workspace layout (bytes)
  char* ws = (char*)d_ws;
  unsigned short* P1 = (unsigned short*)(ws);                 // FF1 z=1 partial, 25165824 B
  unsigned short* Y = (unsigned short*)(ws + 12582912);       // 6291456 (bf16) — inside P1 range; disjoint lifetimes
  float* SPROJ  = (float*)(ws + 25165824);            // 16384
  float* EPROJ  = (float*)(ws + 25182208);            // 16384
  float* BQKV   = (float*)(ws + 25198592);            // 36864
  unsigned short* XB    = (unsigned short*)(ws + 25235456);   // 6291456 (residual stream, bf16)
  unsigned short* QKV   = (unsigned short*)(ws + 31526912);   // 18874368
  unsigned short* CTX   = (unsigned short*)(ws + 50401280);   // 6291456
  unsigned short* HBUF  = (unsigned short*)(ws + 56692736);   // 25165824
  unsigned short* WTALL = (unsigned short*)(ws + 81858560);   // 56623104
  // aliases (regions dead at time of use):
  unsigned short* Y2    = (unsigned short*)(ws + 31526912);   // Wo/FF2 partials (3x6.29MB) over QKV (dead after attn)
  unsigned short* QKVP  = (unsigned short*)(ws + 56692736);   // QKV z=1 partial (18.87MB) over HBUF (dead until FF1)

  k_prep_weights<<<6912, 256, 0, stream>>>(Wq, Wk, Wv, Wo, W1, W2, WTALL);
  k_prep_bias<<<36, 256, 0, stream>>>(bq, bk, bv, BQKV);
  k_embed_ln<<<4096, 256, 0, stream>>>(ids, tts, we, pe, te, eg, ebv, XB);

  for (int l = 0; l < NL_; l++){
    unsigned short* wt = WTALL + (size_t)l * 7077888;
    // QKV: M=4096 N=2304 K=768, split-K x2 -> 1152 blocks; z=1 partial in QKVP,
    // reduce folded into attention (reads QKV + QKVP).
    k_gemm<0><<<dim3(18, 32, 2), 256, 0, stream>>>(XB, wt, BQKV + l * 2304, QKV, QKVP, 4096, 2304, 768, 384);
    k_attn_mfma<<<dim3(8, 12, 8), 256, 0, stream>>>(QKV, QKVP, mask, CTX);
    // Wo: N=768 K=768, split-K x4 -> 768 blocks; partials z=1..3 in Y2
    k_gemm<0><<<dim3(6, 32, 4), 256, 0, stream>>>(CTX, wt + 1769472, bo + l * 768, Y, Y2, 4096, 768, 768, 192);
    k_add_ln<<<4096, 256, 0, stream>>>(XB, Y, Y2, 3, ag + l * 768, ab + l * 768);
    // FF1: N=3072 K=768, split-K x2 -> 1536 blocks; z=0 (+bias) -> HBUF, z=1 -> P1; gelu in reduce
    k_gemm<0><<<dim3(24, 32, 2), 256, 0, stream>>>(XB, wt + 2359296, b1 + l * 3072, HBUF, P1, 4096, 3072, 768, 384);
    k_gelu_reduce<<<6144, 256, 0, stream>>>(HBUF, P1);
    // FF2: N=768 K=3072, split-K x4 -> 768 blocks; partials z=1..3 in Y2
    k_gemm<0><<<dim3(6, 32, 4), 256, 0, stream>>>(HBUF, wt + 4718592, b2 + l * 768, Y, Y2, 4096, 768, 3072, 768);
    k_add_ln<<<4096, 256, 0, stream>>>(XB, Y, Y2, 3, fg + l * 768, fb + l * 768);
  }

  k_heads<<<4096, 256, 0, stream>>>(XB, sw, sb, ew, ebd, mw, out, SPROJ, EPROJ);
  k_match<<<2048, 256, 0, stream>>>(SPROJ, EPROJ, mb, out);
}

// Round 10
// 662.695 us; speedup vs baseline: 1.1462x; 1.1462x over previous
//
#include <hip/hip_runtime.h>

#define B_   8
#define L_   512
#define H_   768
#define NH_  12
#define DFF_ 3072
#define NL_  4
#define HD_  64
#define M_   4096

typedef __bf16 bf16x8 __attribute__((ext_vector_type(8)));
typedef float f32x4 __attribute__((ext_vector_type(4)));
typedef unsigned short u16x8 __attribute__((ext_vector_type(8)));

__device__ inline float bf2f(unsigned short u){
  union { unsigned int i; float f; } v; v.i = ((unsigned int)u) << 16; return v.f;
}
__device__ inline unsigned short f2bf(float f){
  union { float f; unsigned int i; } v; v.f = f;
  unsigned int x = v.i;
  return (unsigned short)((x + 0x7fffu + ((x >> 16) & 1u)) >> 16);
}

// ---------------- weight prep: transpose fp32 [R][C] -> bf16 [C][R] ----------------
// 64x64 tiles, float4 reads (16B/lane), LDS transpose, u16x8 writes (16B/lane).
__global__ __launch_bounds__(256) void k_prep_weights(const float* __restrict__ Wq, const float* __restrict__ Wk,
                               const float* __restrict__ Wv, const float* __restrict__ Wo,
                               const float* __restrict__ W1, const float* __restrict__ W2,
                               unsigned short* __restrict__ wTall){
  __shared__ float tile[64][65];
  int id = blockIdx.x;
  int layer = id / 1728;
  int r = id % 1728;
  unsigned short* wt = wTall + (size_t)layer * 7077888;
  const float* src; unsigned short* dst; int R, C, tr, tilesC;
  if (r < 576){
    int mat = r / 144; tr = r % 144; R = 768; C = 768; tilesC = 12;
    const float* s;
    if (mat == 0) s = Wq; else if (mat == 1) s = Wk; else if (mat == 2) s = Wv; else s = Wo;
    src = s + (size_t)layer * 589824;
    dst = wt + (size_t)mat * 589824;
  } else if (r < 1152){
    tr = r - 576; R = 768; C = 3072; tilesC = 48;
    src = W1 + (size_t)layer * 2359296; dst = wt + 2359296;
  } else {
    tr = r - 1152; R = 3072; C = 768; tilesC = 12;
    src = W2 + (size_t)layer * 2359296; dst = wt + 4718592;
  }
  int r0 = (tr / tilesC) << 6, c0 = (tr % tilesC) << 6;
  int tid = threadIdx.x;
  int tx = tid & 15, ty = tid >> 4;   // 16x16, 4 rows per thread
  #pragma unroll
  for (int i = 0; i < 4; i++){
    int row = ty + i * 16;
    float4 v = *(const float4*)(src + (size_t)(r0 + row) * C + c0 + tx * 4);
    tile[row][tx * 4] = v.x; tile[row][tx * 4 + 1] = v.y;
    tile[row][tx * 4 + 2] = v.z; tile[row][tx * 4 + 3] = v.w;
  }
  __syncthreads();
  int rr = (tid & 7) * 8;
  #pragma unroll
  for (int i = 0; i < 2; i++){
    int col = (tid >> 3) + i * 32;
    u16x8 o;
    #pragma unroll
    for (int j = 0; j < 8; j++) o[j] = f2bf(tile[rr + j][col]);
    *(u16x8*)(dst + (size_t)(c0 + col) * R + r0 + rr) = o;
  }
}

// concat qkv bias per layer: [NL][2304]
__global__ void k_prep_bias(const float* __restrict__ bq, const float* __restrict__ bk,
                            const float* __restrict__ bv, float* __restrict__ out){
  int i = blockIdx.x * 256 + threadIdx.x; // 4*2304
  int layer = i / 2304, c = i % 2304;
  float v;
  if (c < 768) v = bq[layer * 768 + c];
  else if (c < 1536) v = bk[layer * 768 + c - 768];
  else v = bv[layer * 768 + c - 1536];
  out[i] = v;
}

// ---------------- embedding + LN (bf16 out only) ----------------
__global__ __launch_bounds__(256) void k_embed_ln(const int* __restrict__ ids, const int* __restrict__ tts,
                           const float* __restrict__ we, const float* __restrict__ pe,
                           const float* __restrict__ te, const float* __restrict__ g,
                           const float* __restrict__ b,
                           unsigned short* __restrict__ xb){
  int row = blockIdx.x;           // 4096
  int l = row & 511;
  int id = ids[row], tt = tts[row];
  int t = threadIdx.x;            // 256
  float v[3]; float s = 0.f, s2 = 0.f;
  #pragma unroll
  for (int i = 0; i < 3; i++){
    int c = t + i * 256;
    float val = we[(size_t)id * 768 + c] + pe[(size_t)l * 768 + c] + te[(size_t)tt * 768 + c];
    v[i] = val; s += val; s2 += val * val;
  }
  #pragma unroll
  for (int o = 32; o > 0; o >>= 1){ s += __shfl_down(s, o); s2 += __shfl_down(s2, o); }
  __shared__ float red[2][4];
  int wv = t >> 6;
  if ((t & 63) == 0){ red[0][wv] = s; red[1][wv] = s2; }
  __syncthreads();
  s = red[0][0] + red[0][1] + red[0][2] + red[0][3];
  s2 = red[1][0] + red[1][1] + red[1][2] + red[1][3];
  float mean = s * (1.f / 768.f);
  float var = s2 * (1.f / 768.f) - mean * mean;
  float rstd = rsqrtf(var + 1e-12f);
  #pragma unroll
  for (int i = 0; i < 3; i++){
    int c = t + i * 256;
    float nv = (v[i] - mean) * rstd * g[c] + b[c];
    xb[(size_t)row * 768 + c] = f2bf(nv);
  }
}

// ---------------- residual add + N2 bf16 partials + LN, fully vectorized ----------------
// 128 threads; lanes 0..95 each own one u16x8 (8 cols). u16x8 loads throughout (G13).
template<int N2>
__global__ __launch_bounds__(128) void k_add_ln(unsigned short* __restrict__ xb,
                         const unsigned short* __restrict__ y,
                         const unsigned short* __restrict__ y2,
                         const float* __restrict__ g, const float* __restrict__ b){
  int row = blockIdx.x;
  int t = threadIdx.x;
  float v[8];
  float s = 0.f, s2 = 0.f;
  size_t base = (size_t)row * 768 + t * 8;
  if (t < 96){
    u16x8 a = *(const u16x8*)(xb + base);
    u16x8 yy = *(const u16x8*)(y + base);
    #pragma unroll
    for (int j = 0; j < 8; j++) v[j] = bf2f(a[j]) + bf2f(yy[j]);
    #pragma unroll
    for (int q = 0; q < N2; q++){
      u16x8 p = *(const u16x8*)(y2 + (size_t)q * 4096 * 768 + base);
      #pragma unroll
      for (int j = 0; j < 8; j++) v[j] += bf2f(p[j]);
    }
    #pragma unroll
    for (int j = 0; j < 8; j++){ s += v[j]; s2 += v[j] * v[j]; }
  }
  #pragma unroll
  for (int o = 32; o > 0; o >>= 1){ s += __shfl_down(s, o); s2 += __shfl_down(s2, o); }
  __shared__ float red[2][2];
  int wv = t >> 6;
  if ((t & 63) == 0){ red[0][wv] = s; red[1][wv] = s2; }
  __syncthreads();
  s = red[0][0] + red[0][1];
  s2 = red[1][0] + red[1][1];
  float mean = s * (1.f / 768.f);
  float var = s2 * (1.f / 768.f) - mean * mean;
  float rstd = rsqrtf(var + 1e-12f);
  if (t < 96){
    f32x4 g0 = *(const f32x4*)(g + t * 8);
    f32x4 g1 = *(const f32x4*)(g + t * 8 + 4);
    f32x4 b0 = *(const f32x4*)(b + t * 8);
    f32x4 b1 = *(const f32x4*)(b + t * 8 + 4);
    u16x8 o8;
    #pragma unroll
    for (int j = 0; j < 4; j++) o8[j] = f2bf((v[j] - mean) * rstd * g0[j] + b0[j]);
    #pragma unroll
    for (int j = 0; j < 4; j++) o8[4 + j] = f2bf((v[4 + j] - mean) * rstd * g1[j] + b1[j]);
    *(u16x8*)(xb + base) = o8;
  }
}

// ---------------- bf16 MFMA GEMM, m97 structure (single 32KB buffer) + T2 swizzle ----------------
// C[M][N] = A[M][Kslice] @ BT[N][K]^T + bias, bf16 out. blockIdx.z = K-slice;
// z>0 writes bias-free partial to Cout2[(z-1)*M*N]. ACT 0: none; 1: gelu.
// Occupancy is GRID-capped at these shapes (768 blocks = 3 blk/CU); (256,4) allows a
// 4th resident block when split-K grids exceed 1024 blocks.
template<int ACT>
__global__ __launch_bounds__(256, 4) void k_gemm(const unsigned short* __restrict__ A,
                                              const unsigned short* __restrict__ BT,
                                              const float* __restrict__ bias,
                                              unsigned short* __restrict__ Cout,
                                              unsigned short* __restrict__ Cout2,
                                              int M, int N, int K, int Ksub){
  __shared__ __attribute__((aligned(16))) unsigned short smem[16384]; // As | Bs, 32 KB
  unsigned short* As = smem;
  unsigned short* Bs = smem + 8192;
  int tid = threadIdx.x;
  int lane = tid & 63, wave = tid >> 6;
  int lr = lane & 15, lg = lane >> 4;

  // XCD-aware swizzle of flat tile id (nwg % 8 == 0 in all launches)
  int gx = gridDim.x;
  int nwg = gx * gridDim.y;
  int flat = blockIdx.y * gx + blockIdx.x;
  int cpx = nwg >> 3;
  int swz = (flat & 7) * cpx + (flat >> 3);
  int bx = swz % gx, by = swz / gx;

  int bm0 = by * 128, bn0 = bx * 128;
  int wr = wave >> 1, wc = wave & 1;
  int kz = blockIdx.z * Ksub;

  f32x4 acc[4][4];
  #pragma unroll
  for (int m = 0; m < 4; m++)
    #pragma unroll
    for (int n = 0; n < 4; n++)
      acc[m][n] = (f32x4){0.f, 0.f, 0.f, 0.f};

  // per-lane pre-swizzled source column (T2, m173 pattern)
  int scol = (((lane & 7) ^ (lane >> 3)) << 3);
  const unsigned short* gaBase = A + (size_t)(bm0 + (lane >> 3)) * K + kz + scol;
  const unsigned short* gbBase = BT + (size_t)(bn0 + (lane >> 3)) * K + kz + scol;

  int nk = Ksub >> 6;
  for (int t = 0; t < nk; t++){
    if (t) __syncthreads();           // all waves done reading previous tile
    const unsigned short* gA = gaBase + (t << 6);
    const unsigned short* gB = gbBase + (t << 6);
    #pragma unroll
    for (int i = 0; i < 4; i++){
      size_t ro = (size_t)((wave * 4 + i) * 8) * K;
      __builtin_amdgcn_global_load_lds(
        (const __attribute__((address_space(1))) void*)(gA + ro),
        (__attribute__((address_space(3))) void*)(As + (wave * 4 + i) * 512), 16, 0, 0);
      __builtin_amdgcn_global_load_lds(
        (const __attribute__((address_space(1))) void*)(gB + ro),
        (__attribute__((address_space(3))) void*)(Bs + (wave * 4 + i) * 512), 16, 0, 0);
    }
    __syncthreads();                  // vmcnt(0)+barrier: tile resident
    #pragma unroll
    for (int kk = 0; kk < 2; kk++){
      bf16x8 av[4], bv[4];
      #pragma unroll
      for (int m = 0; m < 4; m++)
        av[m] = *(const bf16x8*)(As + (wr * 64 + m * 16 + lr) * 64 + (((4 * kk + lg) ^ (lr & 7)) << 3));
      #pragma unroll
      for (int n = 0; n < 4; n++)
        bv[n] = *(const bf16x8*)(Bs + (wc * 64 + n * 16 + lr) * 64 + (((4 * kk + lg) ^ (lr & 7)) << 3));
      #pragma unroll
      for (int m = 0; m < 4; m++)
        #pragma unroll
        for (int n = 0; n < 4; n++)
          acc[m][n] = __builtin_amdgcn_mfma_f32_16x16x32_bf16(av[m], bv[n], acc[m][n], 0, 0, 0);
    }
  }
  __syncthreads();                    // safe to reuse smem for epilogue

  // epilogue: stage bf16 C tile [128][128] in LDS, then linear coalesced stores
  int r0 = wr * 64 + 4 * lg;
  int c0 = wc * 64 + lr;
  unsigned short* cs = smem;
  bool z0 = (blockIdx.z == 0);
  #pragma unroll
  for (int n = 0; n < 4; n++){
    int c = c0 + 16 * n;
    float bsv = z0 ? bias[bn0 + c] : 0.f;
    #pragma unroll
    for (int m = 0; m < 4; m++)
      #pragma unroll
      for (int j = 0; j < 4; j++){
        float v = acc[m][n][j] + bsv;
        if (ACT == 1) v = 0.5f * v * (1.f + erff(v * 0.70710678118f));
        cs[(r0 + m * 16 + j) * 128 + c] = f2bf(v);
      }
  }
  __syncthreads();
  unsigned short* Cb = z0 ? Cout : (Cout2 + (size_t)(blockIdx.z - 1) * M * N);
  #pragma unroll
  for (int p = 0; p < 8; p++){
    int idx = p * 2048 + tid * 8;
    int row = idx >> 7, col = idx & 127;
    u16x8 v = *(const u16x8*)(cs + idx);
    *(u16x8*)(Cb + (size_t)(bm0 + row) * N + bn0 + col) = v;
  }
}

// ---------------- fused FF1 reduce: h = gelu(h + p1) (bf16, x8 vectorized) ----------------
__global__ __launch_bounds__(256) void k_gelu_reduce(unsigned short* __restrict__ h,
                                                     const unsigned short* __restrict__ p1){
  size_t i = ((size_t)blockIdx.x * 256 + threadIdx.x) * 8;
  u16x8 a = *(const u16x8*)(h + i);
  u16x8 b = *(const u16x8*)(p1 + i);
  u16x8 o;
  #pragma unroll
  for (int j = 0; j < 8; j++){
    float v = bf2f(a[j]) + bf2f(b[j]);
    v = 0.5f * v * (1.f + erff(v * 0.70710678118f));
    o[j] = f2bf(v);
  }
  *(u16x8*)(h + i) = o;
}

// ---------------- MFMA flash attention (single QKV input — L2-resident) ----------------
__global__ __launch_bounds__(256) void k_attn_mfma(const unsigned short* __restrict__ qkv,
                                                   const int* __restrict__ mask,
                                                   unsigned short* __restrict__ ctx){
  int qt = blockIdx.x, h = blockIdx.y, b = blockIdx.z;
  int tid = threadIdx.x;
  int lane = tid & 63, w = tid >> 6;
  int lr = lane & 15, lg = lane >> 4;

  __shared__ __attribute__((aligned(16))) unsigned short Ks[64][72];
  __shared__ __attribute__((aligned(16))) unsigned short VsT[64][72];
  __shared__ __attribute__((aligned(16))) unsigned short Ps[4][16][72];
  __shared__ float biasS[64];

  int qrow = b * 512 + qt * 64 + w * 16 + lr;
  const unsigned short* qp = qkv + (size_t)qrow * 2304 + h * 64 + lg * 8;
  bf16x8 qa[2];
  qa[0] = *(const bf16x8*)(qp);
  qa[1] = *(const bf16x8*)(qp + 32);

  f32x4 oacc[4];
  #pragma unroll
  for (int dt = 0; dt < 4; dt++) oacc[dt] = (f32x4){0.f, 0.f, 0.f, 0.f};
  float mrow[4], lrow[4];
  #pragma unroll
  for (int j = 0; j < 4; j++){ mrow[j] = -1e30f; lrow[j] = 0.f; }

  for (int c = 0; c < 8; c++){
    __syncthreads();
    {
      int r = tid >> 2, d0 = (tid & 3) << 4;
      const unsigned short* kp = qkv + (size_t)(b * 512 + c * 64 + r) * 2304 + 768 + h * 64 + d0;
      u16x8 k0 = *(const u16x8*)kp;
      u16x8 k1 = *(const u16x8*)(kp + 8);
      *(u16x8*)(&Ks[r][d0]) = k0;
      *(u16x8*)(&Ks[r][d0 + 8]) = k1;
    }
    {
      int kv = tid & 63, d0 = (tid >> 6) << 4;
      const unsigned short* vp = qkv + (size_t)(b * 512 + c * 64 + kv) * 2304 + 1536 + h * 64 + d0;
      u16x8 v0 = *(const u16x8*)vp;
      u16x8 v1 = *(const u16x8*)(vp + 8);
      #pragma unroll
      for (int j2 = 0; j2 < 8; j2++){
        VsT[d0 + j2][kv] = (unsigned short)v0[j2];
        VsT[d0 + 8 + j2][kv] = (unsigned short)v1[j2];
      }
    }
    if (tid < 64) biasS[tid] = (1.f - (float)mask[b * 512 + c * 64 + tid]) * -1e9f;
    __syncthreads();

    f32x4 sacc[4];
    #pragma unroll
    for (int n = 0; n < 4; n++) sacc[n] = (f32x4){0.f, 0.f, 0.f, 0.f};
    #pragma unroll
    for (int kk = 0; kk < 2; kk++){
      bf16x8 kb[4];
      #pragma unroll
      for (int n = 0; n < 4; n++)
        kb[n] = *(const bf16x8*)(&Ks[lr + 16 * n][lg * 8 + 32 * kk]);
      #pragma unroll
      for (int n = 0; n < 4; n++)
        sacc[n] = __builtin_amdgcn_mfma_f32_16x16x32_bf16(qa[kk], kb[n], sacc[n], 0, 0, 0);
    }

    float pv[4][4];
    #pragma unroll
    for (int n = 0; n < 4; n++){
      float bsv = biasS[lr + 16 * n];
      #pragma unroll
      for (int j = 0; j < 4; j++) pv[n][j] = sacc[n][j] * 0.125f + bsv;
    }
    #pragma unroll
    for (int j = 0; j < 4; j++){
      float mx = fmaxf(fmaxf(pv[0][j], pv[1][j]), fmaxf(pv[2][j], pv[3][j]));
      mx = fmaxf(mx, __shfl_xor(mx, 1));
      mx = fmaxf(mx, __shfl_xor(mx, 2));
      mx = fmaxf(mx, __shfl_xor(mx, 4));
      mx = fmaxf(mx, __shfl_xor(mx, 8));
      float mnew = fmaxf(mrow[j], mx);
      float corr = __expf(mrow[j] - mnew);
      float ps = 0.f;
      #pragma unroll
      for (int n = 0; n < 4; n++){
        pv[n][j] = __expf(pv[n][j] - mnew);
        ps += pv[n][j];
      }
      ps += __shfl_xor(ps, 1);
      ps += __shfl_xor(ps, 2);
      ps += __shfl_xor(ps, 4);
      ps += __shfl_xor(ps, 8);
      lrow[j] = lrow[j] * corr + ps;
      mrow[j] = mnew;
      #pragma unroll
      for (int dt = 0; dt < 4; dt++) oacc[dt][j] *= corr;
    }

    #pragma unroll
    for (int n = 0; n < 4; n++)
      #pragma unroll
      for (int j = 0; j < 4; j++)
        Ps[w][4 * lg + j][lr + 16 * n] = f2bf(pv[n][j]);

    #pragma unroll
    for (int kk = 0; kk < 2; kk++){
      bf16x8 pa = *(const bf16x8*)(&Ps[w][lr][lg * 8 + 32 * kk]);
      bf16x8 vb[4];
      #pragma unroll
      for (int dt = 0; dt < 4; dt++)
        vb[dt] = *(const bf16x8*)(&VsT[lr + 16 * dt][lg * 8 + 32 * kk]);
      #pragma unroll
      for (int dt = 0; dt < 4; dt++)
        oacc[dt] = __builtin_amdgcn_mfma_f32_16x16x32_bf16(pa, vb[dt], oacc[dt], 0, 0, 0);
    }
  }

  #pragma unroll
  for (int j = 0; j < 4; j++){
    float inv = 1.f / lrow[j];
    int row = b * 512 + qt * 64 + w * 16 + 4 * lg + j;
    unsigned short* o = ctx + (size_t)row * 768 + h * 64;
    #pragma unroll
    for (int dt = 0; dt < 4; dt++)
      o[lr + 16 * dt] = f2bf(oacc[dt][j] * inv);
  }
}

// ---------------- span heads (bf16 input) ----------------
__global__ __launch_bounds__(256) void k_heads(const unsigned short* __restrict__ x,
                        const float* __restrict__ sw, const float* __restrict__ sb,
                        const float* __restrict__ ew, const float* __restrict__ eb,
                        const float* __restrict__ mw,
                        float* __restrict__ out, float* __restrict__ sproj, float* __restrict__ eproj){
  int row = blockIdx.x;
  int t = threadIdx.x;
  float a0 = 0.f, a1 = 0.f, a2 = 0.f, a3 = 0.f;
  #pragma unroll
  for (int i = 0; i < 3; i++){
    int c = t + i * 256;
    float v = bf2f(x[(size_t)row * 768 + c]);
    a0 += v * sw[c]; a1 += v * ew[c]; a2 += v * mw[c]; a3 += v * mw[768 + c];
  }
  #pragma unroll
  for (int o = 32; o > 0; o >>= 1){
    a0 += __shfl_down(a0, o); a1 += __shfl_down(a1, o);
    a2 += __shfl_down(a2, o); a3 += __shfl_down(a3, o);
  }
  __shared__ float red[4][4];
  int wv = t >> 6;
  if ((t & 63) == 0){ red[0][wv] = a0; red[1][wv] = a1; red[2][wv] = a2; red[3][wv] = a3; }
  __syncthreads();
  if (t == 0){
    float s0 = red[0][0] + red[0][1] + red[0][2] + red[0][3];
    float s1 = red[1][0] + red[1][1] + red[1][2] + red[1][3];
    float s2 = red[2][0] + red[2][1] + red[2][2] + red[2][3];
    float s3 = red[3][0] + red[3][1] + red[3][2] + red[3][3];
    out[row] = s0 + sb[0];
    out[4096 + row] = s1 + eb[0];
    sproj[row] = s2;
    eproj[row] = s3;
  }
}

__global__ __launch_bounds__(256) void k_match(const float* __restrict__ sproj, const float* __restrict__ eproj,
                        const float* __restrict__ mb, float* __restrict__ out){
  int idx = blockIdx.x * 256 + threadIdx.x;
  int j4 = idx & 127;
  int rest = idx >> 7;
  float sp = sproj[rest] + mb[0];
  const float* ep = eproj + ((rest >> 9) << 9) + j4 * 4;
  float4 r;
  r.x = sp + ep[0]; r.y = sp + ep[1]; r.z = sp + ep[2]; r.w = sp + ep[3];
  ((float4*)(out + 8192))[idx] = r;
}

extern "C" void kernel_launch(void* const* d_in, const int* in_sizes, int n_in,
                              void* d_out, int out_size, void* d_ws, size_t ws_size,
                              hipStream_t stream){
  (void)in_sizes; (void)n_in; (void)out_size; (void)ws_size;
  const int*   ids  = (const int*)d_in[0];
  const int*   tts  = (const int*)d_in[1];
  const int*   mask = (const int*)d_in[2];
  const float* we   = (const float*)d_in[3];
  const float* pe   = (const float*)d_in[4];
  const float* te   = (const float*)d_in[5];
  const float* eg   = (const float*)d_in[6];
  const float* ebv  = (const float*)d_in[7];
  const float* Wq   = (const float*)d_in[8];
  const float* bq   = (const float*)d_in[9];
  const float* Wk   = (const float*)d_in[10];
  const float* bk   = (const float*)d_in[11];
  const float* Wv   = (const float*)d_in[12];
  const float* bv   = (const float*)d_in[13];
  const float* Wo   = (const float*)d_in[14];
  const float* bo   = (const float*)d_in[15];
  const float* ag   = (const float*)d_in[16];
  const float* ab   = (const float*)d_in[17];
  const float* W1   = (const float*)d_in[18];
  const float* b1   = (const float*)d_in[19];
  const float* W2   = (const float*)d_in[20];
  const float* b2   = (const float*)d_in[21];
  const float* fg   = (const float*)d_in[22];
  const float* fb   = (const float*)d_in[23];
  const float* sw   = (const float*)d_in[24];
  const float* sb   = (const float*)d_in[25];
  const float* ew   = (const float*)d_in[26];
  const float* ebd  = (const float*)d_in[27];
  const float* mw   = (const float*)d_in[28];
  const float* mb   = (const float*)d_in[29];
  float* out = (float*)d_out;

  // workspace layout (bytes)
  char* ws = (char*)d_ws;
  unsigned short* P1 = (unsigned short*)(ws);                 // FF1 z=1 partial, 25165824 B
  unsigned short* Y = (unsigned short*)(ws + 12582912);       // 6291456 (bf16) — inside P1 range; disjoint lifetimes
  float* SPROJ  = (float*)(ws + 25165824);            // 16384
  float* EPROJ  = (float*)(ws + 25182208);            // 16384
  float* BQKV   = (float*)(ws + 25198592);            // 36864
  unsigned short* XB    = (unsigned short*)(ws + 25235456);   // 6291456 (residual stream, bf16)
  unsigned short* QKV   = (unsigned short*)(ws + 31526912);   // 18874368
  unsigned short* CTX   = (unsigned short*)(ws + 50401280);   // 6291456
  unsigned short* HBUF  = (unsigned short*)(ws + 56692736);   // 25165824
  unsigned short* WTALL = (unsigned short*)(ws + 81858560);   // 56623104
  // Wo/FF2 partials (3 x 6.29MB) alias the dead-by-then QKV region
  unsigned short* Y2    = (unsigned short*)(ws + 31526912);

  k_prep_weights<<<6912, 256, 0, stream>>>(Wq, Wk, Wv, Wo, W1, W2, WTALL);
  k_prep_bias<<<36, 256, 0, stream>>>(bq, bk, bv, BQKV);
  k_embed_ln<<<4096, 256, 0, stream>>>(ids, tts, we, pe, te, eg, ebv, XB);

  for (int l = 0; l < NL_; l++){
    unsigned short* wt = WTALL + (size_t)l * 7077888;
    // QKV: M=4096 N=2304 K=768 -> 576 blocks (z=1; split variants proved net-negative)
    k_gemm<0><<<dim3(18, 32, 1), 256, 0, stream>>>(XB, wt, BQKV + l * 2304, QKV, nullptr, 4096, 2304, 768, 768);
    k_attn_mfma<<<dim3(8, 12, 8), 256, 0, stream>>>(QKV, mask, CTX);
    // Wo: N=768 K=768, split-K x4 -> 768 blocks; partials z=1..3 in Y2
    k_gemm<0><<<dim3(6, 32, 4), 256, 0, stream>>>(CTX, wt + 1769472, bo + l * 768, Y, Y2, 4096, 768, 768, 192);
    k_add_ln<3><<<4096, 128, 0, stream>>>(XB, Y, Y2, ag + l * 768, ab + l * 768);
    // FF1: N=3072 K=768, split-K x2 -> 1536 blocks (4 blk/CU via (256,4)); gelu in reduce
    k_gemm<0><<<dim3(24, 32, 2), 256, 0, stream>>>(XB, wt + 2359296, b1 + l * 3072, HBUF, P1, 4096, 3072, 768, 384);
    k_gelu_reduce<<<6144, 256, 0, stream>>>(HBUF, P1);
    // FF2: N=768 K=3072, split-K x4 -> 768 blocks; partials z=1..3 in Y2
    k_gemm<0><<<dim3(6, 32, 4), 256, 0, stream>>>(HBUF, wt + 4718592, b2 + l * 768, Y, Y2, 4096, 768, 3072, 768);
    k_add_ln<3><<<4096, 128, 0, stream>>>(XB, Y, Y2, fg + l * 768, fb + l * 768);
  }

  k_heads<<<4096, 256, 0, stream>>>(XB, sw, sb, ew, ebd, mw, out, SPROJ, EPROJ);
  k_match<<<2048, 256, 0, stream>>>(SPROJ, EPROJ, mb, out);
}